// Round 1
// baseline (89.706 us; speedup 1.0000x reference)
//
#include <hip/hip_runtime.h>
#include <hip/hip_bf16.h>

// Problem: SEQ=192, BATCH=2, C_P=128, C=32, C_I=128
// out[b,k,i,j] = ( sum_{c,d} p1[b,i,c] p2[b,j,d] Wk[k,c,d] + bout[k] ) / 2
// p1 = LN(p) @ W1^T + b1 ; p2 = LN(p) @ W2^T + b2 ; Wk = Wout.reshape(128,32,32)

#define SEQ 192
#define BATCH 2
#define CP 128
#define CDIM 32
#define CI 128

typedef __attribute__((ext_vector_type(8))) short bf16x8;   // 8 bf16 = 4 VGPRs
typedef __attribute__((ext_vector_type(4))) float f32x4;

static __device__ __forceinline__ short f2bf(float f) {
    unsigned u = __builtin_bit_cast(unsigned, f);
    u += 0x7fffu + ((u >> 16) & 1u);   // round-to-nearest-even
    return (short)(u >> 16);
}

// ---------------------------------------------------------------------------
// Kernel A: fused LayerNorm + dual projection. One block per (s,b) row.
// Writes p1 as bf16 [b][s][c] (c contiguous) and p2 likewise, with p2
// pre-scaled by 0.5 (the /B fold).
// ---------------------------------------------------------------------------
__global__ __launch_bounds__(128) void opm_pre(
    const float* __restrict__ p, const float* __restrict__ gamma,
    const float* __restrict__ beta, const float* __restrict__ W1,
    const float* __restrict__ b1, const float* __restrict__ W2,
    const float* __restrict__ b2,
    short* __restrict__ p1ws, short* __restrict__ p2ws)
{
    int row = blockIdx.x;          // s*BATCH + b
    int s = row >> 1, b = row & 1;
    int t = threadIdx.x;

    __shared__ float pns[CP];
    __shared__ float red[4];
    __shared__ float part[CP];

    float x = p[s * (BATCH * CP) + b * CP + t];
    float s1 = x, s2 = x * x;
    #pragma unroll
    for (int off = 32; off; off >>= 1) {
        s1 += __shfl_down(s1, off);
        s2 += __shfl_down(s2, off);
    }
    int wave = t >> 6, lane = t & 63;
    if (lane == 0) { red[wave * 2] = s1; red[wave * 2 + 1] = s2; }
    __syncthreads();
    float tot  = red[0] + red[2];
    float tot2 = red[1] + red[3];
    float mu  = tot * (1.0f / CP);
    float var = tot2 * (1.0f / CP) - mu * mu;
    float rs  = rsqrtf(var + 1e-5f);
    pns[t] = (x - mu) * rs * gamma[t] + beta[t];
    __syncthreads();

    // 64 dot products of length 128, split in halves across 128 threads.
    int c = t & 63, half = t >> 6;
    const float* wrow = (c < CDIM ? W1 + c * CP : W2 + (c - CDIM) * CP) + half * 64;
    const float4* pn4 = (const float4*)(pns + half * 64);
    const float4* w4p = (const float4*)wrow;
    float acc = 0.0f;
    #pragma unroll
    for (int i = 0; i < 16; ++i) {
        float4 w4 = w4p[i];
        float4 pn = pn4[i];
        acc += w4.x * pn.x + w4.y * pn.y + w4.z * pn.z + w4.w * pn.w;
    }
    part[t] = acc;
    __syncthreads();
    if (t < 64) {
        float d = part[t] + part[t + 64];
        if (c < CDIM) {
            p1ws[(b * SEQ + s) * CDIM + c] = f2bf(d + b1[c]);
        } else {
            p2ws[(b * SEQ + s) * CDIM + (c - CDIM)] =
                f2bf(0.5f * (d + b2[c - CDIM]));
        }
    }
}

// ---------------------------------------------------------------------------
// Kernel B: one block per (b,k). Phase 1 builds T2^T[j][c] = sum_d
// p2h[b,j,d]*Wk[k,c,d] via MFMA into LDS (bf16, padded rows). Phase 2 does the
// 192x192 GEMM out[i,j] = sum_c p1[b,i,c]*T2^T[j][c] + 0.5*bout[k].
// ---------------------------------------------------------------------------
#define T2PAD 40   // row stride in bf16 elems (80B = 20 dwords -> conflict-free)

__global__ __launch_bounds__(256) void opm_main(
    const short* __restrict__ p1ws,   // [B][SEQ][32] bf16
    const short* __restrict__ p2ws,   // [B][SEQ][32] bf16 (pre-scaled 0.5)
    const float* __restrict__ Wout,   // [128][1024]
    const float* __restrict__ bout,   // [128]
    float* __restrict__ out)          // [B][128][192][192]
{
    int blk = blockIdx.x;             // b*CI + k
    int b = blk >> 7, k = blk & 127;
    int tid  = threadIdx.x;
    int wave = tid >> 6, lane = tid & 63;
    int l15  = lane & 15, quad = lane >> 4;

    __shared__ short t2s[SEQ * T2PAD];

    // ---- Phase 1: T2^T (M=j=192, N=c=32, K=d=32) ----
    const float* wk = Wout + k * (CDIM * CDIM);
    #pragma unroll
    for (int mi = 0; mi < 3; ++mi) {
        int j0 = (wave + mi * 4) * 16;
        bf16x8 afrag = *(const bf16x8*)(p2ws + (b * SEQ + j0 + l15) * CDIM + quad * 8);
        #pragma unroll
        for (int ni = 0; ni < 2; ++ni) {
            int c0 = ni * 16;
            const float* wrow = wk + (c0 + l15) * CDIM + quad * 8;
            bf16x8 bfrag;
            #pragma unroll
            for (int e = 0; e < 8; ++e) bfrag[e] = f2bf(wrow[e]);
            f32x4 acc = {0.0f, 0.0f, 0.0f, 0.0f};
            acc = __builtin_amdgcn_mfma_f32_16x16x32_bf16(afrag, bfrag, acc, 0, 0, 0);
            #pragma unroll
            for (int r = 0; r < 4; ++r)
                t2s[(j0 + quad * 4 + r) * T2PAD + c0 + l15] = f2bf(acc[r]);
        }
    }
    __syncthreads();

    // ---- Phase 2: out tile (M=i=192, N=j=192, K=c=32) ----
    float biask = 0.5f * bout[k];
    const short* p1b = p1ws + b * SEQ * CDIM;
    #pragma unroll
    for (int ii = 0; ii < 3; ++ii) {
        int i0 = (wave * 3 + ii) * 16;
        bf16x8 afrag = *(const bf16x8*)(p1b + (i0 + l15) * CDIM + quad * 8);
        #pragma unroll
        for (int jt = 0; jt < 12; ++jt) {
            int j0 = jt * 16;
            bf16x8 bfrag = *(const bf16x8*)(t2s + (j0 + l15) * T2PAD + quad * 8);
            f32x4 acc = {biask, biask, biask, biask};
            acc = __builtin_amdgcn_mfma_f32_16x16x32_bf16(afrag, bfrag, acc, 0, 0, 0);
            float* o = out + ((blk * SEQ) + i0 + quad * 4) * SEQ + j0 + l15;
            #pragma unroll
            for (int r = 0; r < 4; ++r)
                o[r * SEQ] = acc[r];
        }
    }
}

extern "C" void kernel_launch(void* const* d_in, const int* in_sizes, int n_in,
                              void* d_out, int out_size, void* d_ws, size_t ws_size,
                              hipStream_t stream) {
    const float* p     = (const float*)d_in[0];
    const float* gamma = (const float*)d_in[1];
    const float* beta  = (const float*)d_in[2];
    const float* W1    = (const float*)d_in[3];
    const float* b1    = (const float*)d_in[4];
    const float* W2    = (const float*)d_in[5];
    const float* b2    = (const float*)d_in[6];
    const float* Wout  = (const float*)d_in[7];
    const float* bout  = (const float*)d_in[8];
    float* out = (float*)d_out;

    short* p1ws = (short*)d_ws;                      // 2*192*32 bf16
    short* p2ws = p1ws + BATCH * SEQ * CDIM;         // 2*192*32 bf16

    opm_pre<<<SEQ * BATCH, 128, 0, stream>>>(p, gamma, beta, W1, b1, W2, b2,
                                             p1ws, p2ws);
    opm_main<<<BATCH * CI, 256, 0, stream>>>(p1ws, p2ws, Wout, bout, out);
}

// Round 2
// 88.781 us; speedup vs baseline: 1.0104x; 1.0104x over previous
//
#include <hip/hip_runtime.h>
#include <hip/hip_bf16.h>

// Problem: SEQ=192, BATCH=2, C_P=128, C=32, C_I=128
// out[b,k,i,j] = ( sum_{c,d} p1[b,i,c] p2[b,j,d] Wk[k,c,d] + bout[k] ) / 2
// p1 = LN(p) @ W1^T + b1 ; p2 = LN(p) @ W2^T + b2 ; Wk = Wout.reshape(128,32,32)

#define SEQ 192
#define BATCH 2
#define CP 128
#define CDIM 32
#define CI 128

typedef __attribute__((ext_vector_type(8))) short bf16x8;   // 8 bf16 = 4 VGPRs
typedef __attribute__((ext_vector_type(4))) float f32x4;

static __device__ __forceinline__ short f2bf(float f) {
    unsigned u = __builtin_bit_cast(unsigned, f);
    u += 0x7fffu + ((u >> 16) & 1u);   // round-to-nearest-even
    return (short)(u >> 16);
}

// ---------------------------------------------------------------------------
// Kernel A: fused LayerNorm + dual projection. One block per (s,b) row.
// Writes p1 as bf16 [b][s][c] (c contiguous) and p2 likewise, with p2
// pre-scaled by 0.5 (the /B fold).
// ---------------------------------------------------------------------------
__global__ __launch_bounds__(128) void opm_pre(
    const float* __restrict__ p, const float* __restrict__ gamma,
    const float* __restrict__ beta, const float* __restrict__ W1,
    const float* __restrict__ b1, const float* __restrict__ W2,
    const float* __restrict__ b2,
    short* __restrict__ p1ws, short* __restrict__ p2ws)
{
    int row = blockIdx.x;          // s*BATCH + b
    int s = row >> 1, b = row & 1;
    int t = threadIdx.x;

    __shared__ float pns[CP];
    __shared__ float red[4];
    __shared__ float part[CP];

    float x = p[s * (BATCH * CP) + b * CP + t];
    float s1 = x, s2 = x * x;
    #pragma unroll
    for (int off = 32; off; off >>= 1) {
        s1 += __shfl_down(s1, off);
        s2 += __shfl_down(s2, off);
    }
    int wave = t >> 6, lane = t & 63;
    if (lane == 0) { red[wave * 2] = s1; red[wave * 2 + 1] = s2; }
    __syncthreads();
    float tot  = red[0] + red[2];
    float tot2 = red[1] + red[3];
    float mu  = tot * (1.0f / CP);
    float var = tot2 * (1.0f / CP) - mu * mu;
    float rs  = rsqrtf(var + 1e-5f);
    pns[t] = (x - mu) * rs * gamma[t] + beta[t];
    __syncthreads();

    // 64 dot products of length 128, split in halves across 128 threads.
    int c = t & 63, half = t >> 6;
    const float* wrow = (c < CDIM ? W1 + c * CP : W2 + (c - CDIM) * CP) + half * 64;
    const float4* pn4 = (const float4*)(pns + half * 64);
    const float4* w4p = (const float4*)wrow;
    float acc = 0.0f;
    #pragma unroll
    for (int i = 0; i < 16; ++i) {
        float4 w4 = w4p[i];
        float4 pn = pn4[i];
        acc += w4.x * pn.x + w4.y * pn.y + w4.z * pn.z + w4.w * pn.w;
    }
    part[t] = acc;
    __syncthreads();
    if (t < 64) {
        float d = part[t] + part[t + 64];
        if (c < CDIM) {
            p1ws[(b * SEQ + s) * CDIM + c] = f2bf(d + b1[c]);
        } else {
            p2ws[(b * SEQ + s) * CDIM + (c - CDIM)] =
                f2bf(0.5f * (d + b2[c - CDIM]));
        }
    }
}

// ---------------------------------------------------------------------------
// Kernel B: one block per (b, k, i-chunk of 48). 4 waves, 256 threads.
// Phase 1: wave w builds T2^T rows j in [48w, 48w+48): T2^T[j][c] =
//   sum_d p2h[b,j,d]*Wk[k,c,d] via MFMA into LDS (bf16, padded rows).
// Phase 2: wave w computes out[i0..i0+47, 48w..48w+47] — reads ONLY its own
//   T2 rows, so no __syncthreads is needed (intra-wave lgkmcnt ordering).
// Grid = 1024 blocks -> 4 blocks/CU, 4 waves/SIMD for latency hiding.
// ---------------------------------------------------------------------------
#define T2PAD 40   // row stride in bf16 elems (80B = 20 dwords)

__global__ __launch_bounds__(256) void opm_main(
    const short* __restrict__ p1ws,   // [B][SEQ][32] bf16
    const short* __restrict__ p2ws,   // [B][SEQ][32] bf16 (pre-scaled 0.5)
    const float* __restrict__ Wout,   // [128][1024]
    const float* __restrict__ bout,   // [128]
    float* __restrict__ out)          // [B][128][192][192]
{
    int bk = blockIdx.x >> 2;         // b*CI + k
    int iq = blockIdx.x & 3;          // which 48-row i chunk
    int b = bk >> 7, k = bk & 127;
    int tid  = threadIdx.x;
    int wave = tid >> 6, lane = tid & 63;
    int l15  = lane & 15, quad = lane >> 4;

    __shared__ short t2s[SEQ * T2PAD];

    // ---- Phase 1: T2^T (M=j, N=c=32, K=d=32), wave-private j range ----
    const float* wk = Wout + k * (CDIM * CDIM);
    bf16x8 bfr[2];
    #pragma unroll
    for (int ni = 0; ni < 2; ++ni) {
        const float* wrow = wk + (ni * 16 + l15) * CDIM + quad * 8;
        #pragma unroll
        for (int e = 0; e < 8; ++e) bfr[ni][e] = f2bf(wrow[e]);
    }
    #pragma unroll
    for (int mi = 0; mi < 3; ++mi) {
        int j0 = (wave * 3 + mi) * 16;
        bf16x8 afrag = *(const bf16x8*)(p2ws + (b * SEQ + j0 + l15) * CDIM + quad * 8);
        #pragma unroll
        for (int ni = 0; ni < 2; ++ni) {
            f32x4 acc = {0.0f, 0.0f, 0.0f, 0.0f};
            acc = __builtin_amdgcn_mfma_f32_16x16x32_bf16(afrag, bfr[ni], acc, 0, 0, 0);
            #pragma unroll
            for (int r = 0; r < 4; ++r)
                t2s[(j0 + quad * 4 + r) * T2PAD + ni * 16 + l15] = f2bf(acc[r]);
        }
    }

    // ---- Phase 2: out tile (M=i 48 rows, N=j 48 cols/wave, K=c=32) ----
    float biask = 0.5f * bout[k];
    const short* p1b = p1ws + b * SEQ * CDIM;
    float* obase = out + (size_t)bk * (SEQ * SEQ);
    #pragma unroll
    for (int ii = 0; ii < 3; ++ii) {
        int i0 = iq * 48 + ii * 16;
        bf16x8 afrag = *(const bf16x8*)(p1b + (i0 + l15) * CDIM + quad * 8);
        #pragma unroll
        for (int jj = 0; jj < 3; ++jj) {
            int j0 = (wave * 3 + jj) * 16;
            bf16x8 bfrag = *(const bf16x8*)(t2s + (j0 + l15) * T2PAD + quad * 8);
            f32x4 acc = {biask, biask, biask, biask};
            acc = __builtin_amdgcn_mfma_f32_16x16x32_bf16(afrag, bfrag, acc, 0, 0, 0);
            float* o = obase + (i0 + quad * 4) * SEQ + j0 + l15;
            #pragma unroll
            for (int r = 0; r < 4; ++r)
                o[r * SEQ] = acc[r];
        }
    }
}

extern "C" void kernel_launch(void* const* d_in, const int* in_sizes, int n_in,
                              void* d_out, int out_size, void* d_ws, size_t ws_size,
                              hipStream_t stream) {
    const float* p     = (const float*)d_in[0];
    const float* gamma = (const float*)d_in[1];
    const float* beta  = (const float*)d_in[2];
    const float* W1    = (const float*)d_in[3];
    const float* b1    = (const float*)d_in[4];
    const float* W2    = (const float*)d_in[5];
    const float* b2    = (const float*)d_in[6];
    const float* Wout  = (const float*)d_in[7];
    const float* bout  = (const float*)d_in[8];
    float* out = (float*)d_out;

    short* p1ws = (short*)d_ws;                      // 2*192*32 bf16
    short* p2ws = p1ws + BATCH * SEQ * CDIM;         // 2*192*32 bf16

    opm_pre<<<SEQ * BATCH, 128, 0, stream>>>(p, gamma, beta, W1, b1, W2, b2,
                                             p1ws, p2ws);
    opm_main<<<BATCH * CI * 4, 256, 0, stream>>>(p1ws, p2ws, Wout, bout, out);
}